// Round 1
// baseline (120.926 us; speedup 1.0000x reference)
//
#include <hip/hip_runtime.h>

// Viterbi trellis quantizer: S=1024 states, K=2 (4 predecessors), CHUNK=4,
// block_size=16 -> T=64 steps/chain, B=4096 chains (16x16 blocks of 1024^2).
//
// Mapping: one 64-lane wave per chain, 4 chains per 256-thread workgroup.
// Grouped-min state M[p] = min_j alpha[p + 256 j] (p in [0,256)) carried in
// LDS (1 KB/chain); backpointers 2-bit packed in LDS (4 KB/chain). Codebook
// rows needed by a lane (s = 4*lane + c + 256*j) are step-invariant -> kept
// in registers (-2*row and ||row||^2), reused across all 64 steps.

#define COLS      1024
#define T_STEPS   64
#define REC_SIZE  (1024 * 1024)

__global__ __launch_bounds__(256) void viterbi_q(
    const float* __restrict__ arr,
    const float* __restrict__ cbook,
    float* __restrict__ out)
{
    const int tid   = threadIdx.x;
    const int wid   = tid >> 6;      // wave id in block = chain slot
    const int lane  = tid & 63;
    const int chain = (blockIdx.x << 2) | wid;   // 0..4095
    const int rb    = chain >> 6;    // block-row
    const int cb    = chain & 63;    // block-col

    __shared__ __align__(16) float tile[4][256];   // x chunks for the chain
    __shared__ __align__(16) float Mst[4][256];    // grouped-min state M[p]
    __shared__ unsigned char Jb[4][63 * 64];       // packed backpointers
    __shared__ int st_lds[4][64];                  // traced-back states

    // ---- stage this chain's 16x16 tile into LDS (tile[e], e = r*16 + c) ----
    {
        const int r  = lane >> 2;
        const int c4 = (lane & 3) << 2;
        float4 v = *(const float4*)(arr + (rb * 16 + r) * COLS + cb * 16 + c4);
        *(float4*)&tile[wid][lane << 2] = v;
    }
    // M starts at 0: iteration t=0 then computes alpha0 = cost(x0) exactly.
    *(float4*)&Mst[wid][lane << 2] = make_float4(0.f, 0.f, 0.f, 0.f);

    // ---- codebook rows for this lane's 16 states: s = 4*lane + c + 256*j ----
    float4 a[16];   // -2 * codebook row
    float  nrm[16]; // ||row||^2
    #pragma unroll
    for (int j = 0; j < 4; ++j) {
        #pragma unroll
        for (int c = 0; c < 4; ++c) {
            const int row = (lane << 2) + c + (j << 8);
            float4 v = *(const float4*)(cbook + row * 4);
            nrm[j * 4 + c] = v.x * v.x + v.y * v.y + v.z * v.z + v.w * v.w;
            a[j * 4 + c]   = make_float4(-2.f * v.x, -2.f * v.y,
                                         -2.f * v.z, -2.f * v.w);
        }
    }

    // ---- forward recursion, t = 0..62: store backpointers J_t ----
    for (int t = 0; t < T_STEPS - 1; ++t) {
        float4 xt = *(const float4*)&tile[wid][t << 2];   // broadcast read
        const float xn = xt.x * xt.x + xt.y * xt.y + xt.z * xt.z + xt.w * xt.w;
        float mj[4];
        #pragma unroll
        for (int j = 0; j < 4; ++j)
            mj[j] = Mst[wid][lane + 64 * j] + xn;

        float nm[4];
        unsigned bp = 0;
        #pragma unroll
        for (int c = 0; c < 4; ++c) {
            float cand[4];
            #pragma unroll
            for (int j = 0; j < 4; ++j) {
                float acc = nrm[j * 4 + c] + mj[j];
                const float4 av = a[j * 4 + c];
                acc = fmaf(av.x, xt.x, acc);
                acc = fmaf(av.y, xt.y, acc);
                acc = fmaf(av.z, xt.z, acc);
                acc = fmaf(av.w, xt.w, acc);
                cand[j] = acc;
            }
            const float v = fminf(fminf(cand[0], cand[1]),
                                  fminf(cand[2], cand[3]));
            // first-min index (jnp.argmin tie semantics)
            const int j = (cand[0] == v) ? 0
                        : (cand[1] == v) ? 1
                        : (cand[2] == v) ? 2 : 3;
            nm[c] = v;
            bp |= (unsigned)j << (2 * c);
        }
        // wave-lockstep: all lanes issued their M reads above before this write
        *(float4*)&Mst[wid][lane << 2] = make_float4(nm[0], nm[1], nm[2], nm[3]);
        Jb[wid][t * 64 + lane] = (unsigned char)bp;
    }

    // ---- final step t = 63: full argmin over alpha_63[0..1023] ----
    int bests;
    {
        const int t = T_STEPS - 1;
        float4 xt = *(const float4*)&tile[wid][t << 2];
        const float xn = xt.x * xt.x + xt.y * xt.y + xt.z * xt.z + xt.w * xt.w;
        float mj[4];
        #pragma unroll
        for (int j = 0; j < 4; ++j)
            mj[j] = Mst[wid][lane + 64 * j] + xn;

        float bv = 3.4e38f;
        int   bs = 0;
        #pragma unroll
        for (int j = 0; j < 4; ++j) {      // s ascends with (j, c): first-min ok
            #pragma unroll
            for (int c = 0; c < 4; ++c) {
                float acc = nrm[j * 4 + c] + mj[j];
                const float4 av = a[j * 4 + c];
                acc = fmaf(av.x, xt.x, acc);
                acc = fmaf(av.y, xt.y, acc);
                acc = fmaf(av.z, xt.z, acc);
                acc = fmaf(av.w, xt.w, acc);
                if (acc < bv) { bv = acc; bs = (lane << 2) + c + (j << 8); }
            }
        }
        // lexicographic (value, state) butterfly reduction across the wave
        #pragma unroll
        for (int off = 32; off > 0; off >>= 1) {
            const float ov = __shfl_xor(bv, off, 64);
            const int   os = __shfl_xor(bs, off, 64);
            if (ov < bv || (ov == bv && os < bs)) { bv = ov; bs = os; }
        }
        bests = bs;
    }

    // ---- traceback (serial, lane 0 of each wave) ----
    if (lane == 0) {
        int s = bests;
        st_lds[wid][T_STEPS - 1] = s;
        for (int i = T_STEPS - 2; i >= 0; --i) {
            const int p = s >> 2;
            const unsigned byte = Jb[wid][i * 64 + (p >> 2)];
            const int j = (byte >> (2 * (p & 3))) & 3;
            s = p + (j << 8);
            st_lds[wid][i] = s;
        }
    }
    __syncthreads();

    // ---- outputs: lane i handles step t = i ----
    const int st = st_lds[wid][lane];
    // states_out flat: REC_SIZE + chain*64 + t   (stored as float values)
    out[REC_SIZE + chain * 64 + lane] = (float)st;
    // rec: step t covers elements e = 4t..4t+3 -> row t>>2, cols 4*(t&3)..+3
    const float4 v = *(const float4*)(cbook + st * 4);
    const int r  = lane >> 2;
    const int c4 = (lane & 3) << 2;
    *(float4*)(out + (rb * 16 + r) * COLS + cb * 16 + c4) = v;
}

extern "C" void kernel_launch(void* const* d_in, const int* in_sizes, int n_in,
                              void* d_out, int out_size, void* d_ws, size_t ws_size,
                              hipStream_t stream)
{
    const float* arr   = (const float*)d_in[0];
    const float* cbook = (const float*)d_in[1];
    float* out = (float*)d_out;
    // 4096 chains, 4 chains (waves) per 256-thread block -> 1024 blocks
    viterbi_q<<<dim3(1024), dim3(256), 0, stream>>>(arr, cbook, out);
}

// Round 2
// 109.214 us; speedup vs baseline: 1.1072x; 1.1072x over previous
//
#include <hip/hip_runtime.h>

// Viterbi trellis quantizer: S=1024 states, K=2 (4 predecessors), CHUNK=4,
// block_size=16 -> T=64 steps/chain, B=4096 chains (16x16 blocks of 1024^2).
//
// Mapping: one 64-lane wave per chain, 4 chains per 256-thread workgroup.
// Grouped-min state M[p] = min_j alpha[p + 256 j] (p in [0,256)) carried in
// LDS (1 KB/chain); backpointers 2-bit packed in LDS (4 KB/chain). Codebook
// rows needed by a lane (s = 4*lane + c + 256*j) are step-invariant -> kept
// in registers (-2*row and ||row||^2), reused across all 64 steps.
//
// __launch_bounds__(256, 4): grid is 1024 blocks / 256 CUs = 4 blocks/CU
// = 4 waves/EU, so cap occupancy there -> VGPR budget 128. Without this the
// compiler targeted ~68 VGPRs and SPILLED the 80-reg codebook to scratch
// (R0 evidence: FETCH_SIZE 2.17 GB vs 4 MB of inputs, ~277 VALU inst/step).

#define COLS      1024
#define T_STEPS   64
#define REC_SIZE  (1024 * 1024)

__global__ __launch_bounds__(256, 4) void viterbi_q(
    const float* __restrict__ arr,
    const float* __restrict__ cbook,
    float* __restrict__ out)
{
    const int tid   = threadIdx.x;
    const int wid   = tid >> 6;      // wave id in block = chain slot
    const int lane  = tid & 63;
    const int chain = (blockIdx.x << 2) | wid;   // 0..4095
    const int rb    = chain >> 6;    // block-row
    const int cb    = chain & 63;    // block-col

    __shared__ __align__(16) float tile[4][256];   // x chunks for the chain
    __shared__ __align__(16) float Mst[4][256];    // grouped-min state M[p]
    __shared__ unsigned char Jb[4][63 * 64];       // packed backpointers
    __shared__ int st_lds[4][64];                  // traced-back states

    // ---- stage this chain's 16x16 tile into LDS (tile[e], e = r*16 + c) ----
    {
        const int r  = lane >> 2;
        const int c4 = (lane & 3) << 2;
        float4 v = *(const float4*)(arr + (rb * 16 + r) * COLS + cb * 16 + c4);
        *(float4*)&tile[wid][lane << 2] = v;
    }
    // M starts at 0: iteration t=0 then computes alpha0 = cost(x0) exactly.
    *(float4*)&Mst[wid][lane << 2] = make_float4(0.f, 0.f, 0.f, 0.f);

    // ---- codebook rows for this lane's 16 states: s = 4*lane + c + 256*j ----
    float4 a[16];   // -2 * codebook row
    float  nrm[16]; // ||row||^2
    #pragma unroll
    for (int j = 0; j < 4; ++j) {
        #pragma unroll
        for (int c = 0; c < 4; ++c) {
            const int row = (lane << 2) + c + (j << 8);
            float4 v = *(const float4*)(cbook + row * 4);
            nrm[j * 4 + c] = v.x * v.x + v.y * v.y + v.z * v.z + v.w * v.w;
            a[j * 4 + c]   = make_float4(-2.f * v.x, -2.f * v.y,
                                         -2.f * v.z, -2.f * v.w);
        }
    }

    // hoisted LDS pointers
    const float* __restrict__ tilep = &tile[wid][0];
    float* __restrict__ Mp          = &Mst[wid][0];
    unsigned char* __restrict__ Jp  = &Jb[wid][0];

    // ---- forward recursion, t = 0..62: store backpointers J_t ----
    for (int t = 0; t < T_STEPS - 1; ++t) {
        float4 xt = *(const float4*)&tilep[t << 2];   // broadcast read
        const float xn = xt.x * xt.x + xt.y * xt.y + xt.z * xt.z + xt.w * xt.w;
        float mj[4];
        #pragma unroll
        for (int j = 0; j < 4; ++j)
            mj[j] = Mp[lane + 64 * j] + xn;

        float nm[4];
        unsigned bp = 0;
        #pragma unroll
        for (int c = 0; c < 4; ++c) {
            float cand[4];
            #pragma unroll
            for (int j = 0; j < 4; ++j) {
                float acc = nrm[j * 4 + c] + mj[j];
                const float4 av = a[j * 4 + c];
                acc = fmaf(av.x, xt.x, acc);
                acc = fmaf(av.y, xt.y, acc);
                acc = fmaf(av.z, xt.z, acc);
                acc = fmaf(av.w, xt.w, acc);
                cand[j] = acc;
            }
            const float v = fminf(fminf(cand[0], cand[1]),
                                  fminf(cand[2], cand[3]));
            // first-min index (jnp.argmin tie semantics)
            const int j = (cand[0] == v) ? 0
                        : (cand[1] == v) ? 1
                        : (cand[2] == v) ? 2 : 3;
            nm[c] = v;
            bp |= (unsigned)j << (2 * c);
        }
        // wave-lockstep: all lanes issued their M reads above before this write
        *(float4*)&Mp[lane << 2] = make_float4(nm[0], nm[1], nm[2], nm[3]);
        Jp[t * 64 + lane] = (unsigned char)bp;
    }

    // ---- final step t = 63: full argmin over alpha_63[0..1023] ----
    int bests;
    {
        const int t = T_STEPS - 1;
        float4 xt = *(const float4*)&tilep[t << 2];
        const float xn = xt.x * xt.x + xt.y * xt.y + xt.z * xt.z + xt.w * xt.w;
        float mj[4];
        #pragma unroll
        for (int j = 0; j < 4; ++j)
            mj[j] = Mp[lane + 64 * j] + xn;

        float bv = 3.4e38f;
        int   bs = 0;
        #pragma unroll
        for (int j = 0; j < 4; ++j) {      // s ascends with (j, c): first-min ok
            #pragma unroll
            for (int c = 0; c < 4; ++c) {
                float acc = nrm[j * 4 + c] + mj[j];
                const float4 av = a[j * 4 + c];
                acc = fmaf(av.x, xt.x, acc);
                acc = fmaf(av.y, xt.y, acc);
                acc = fmaf(av.z, xt.z, acc);
                acc = fmaf(av.w, xt.w, acc);
                if (acc < bv) { bv = acc; bs = (lane << 2) + c + (j << 8); }
            }
        }
        // lexicographic (value, state) butterfly reduction across the wave
        #pragma unroll
        for (int off = 32; off > 0; off >>= 1) {
            const float ov = __shfl_xor(bv, off, 64);
            const int   os = __shfl_xor(bs, off, 64);
            if (ov < bv || (ov == bv && os < bs)) { bv = ov; bs = os; }
        }
        bests = bs;
    }

    // ---- traceback (serial, lane 0 of each wave) ----
    if (lane == 0) {
        int s = bests;
        st_lds[wid][T_STEPS - 1] = s;
        for (int i = T_STEPS - 2; i >= 0; --i) {
            const int p = s >> 2;
            const unsigned byte = Jp[i * 64 + (p >> 2)];
            const int j = (byte >> (2 * (p & 3))) & 3;
            s = p + (j << 8);
            st_lds[wid][i] = s;
        }
    }
    __syncthreads();

    // ---- outputs: lane i handles step t = i ----
    const int st = st_lds[wid][lane];
    // states_out flat: REC_SIZE + chain*64 + t   (stored as float values)
    out[REC_SIZE + chain * 64 + lane] = (float)st;
    // rec: step t covers elements e = 4t..4t+3 -> row t>>2, cols 4*(t&3)..+3
    const float4 v = *(const float4*)(cbook + st * 4);
    const int r  = lane >> 2;
    const int c4 = (lane & 3) << 2;
    *(float4*)(out + (rb * 16 + r) * COLS + cb * 16 + c4) = v;
}

extern "C" void kernel_launch(void* const* d_in, const int* in_sizes, int n_in,
                              void* d_out, int out_size, void* d_ws, size_t ws_size,
                              hipStream_t stream)
{
    const float* arr   = (const float*)d_in[0];
    const float* cbook = (const float*)d_in[1];
    float* out = (float*)d_out;
    // 4096 chains, 4 chains (waves) per 256-thread block -> 1024 blocks
    viterbi_q<<<dim3(1024), dim3(256), 0, stream>>>(arr, cbook, out);
}